// Round 1
// baseline (266.447 us; speedup 1.0000x reference)
//
#include <hip/hip_runtime.h>

// Problem constants
#define NB 32
#define NN 1024
#define NC 1024
#define NH 16
#define NA 49

// Workspace layout (float offsets)
#define WQE 0          // [4][1024] effective Q weights (rows 0-2 = w_vel@wq, row 3 = bias)
#define WKE 4096
#define WVE 8192
#define GQK 12288      // [16][4][4] per-head Gram (Wq_eff . Wk_eff^T over head channels)
#define GQQ 12544      // [16][4][4]
#define MH_ 12800      // [16][4][3] Wv_eff @ w_proj per head
#define CH_ 12992      // [16][3][4][3] dwc conv tensor per head
#define DB_ 13568      // [3] global bias: dwc_b@w_proj + b_proj
#define B2T 13824      // [49][1024] transposed agent_bias2
#define ACC 64000      // [32][1024][3] output accumulator (pre-transpose)
#define WS_FLOATS 162304

__device__ __forceinline__ float wave_sum(float v) {
#pragma unroll
    for (int off = 32; off; off >>= 1) v += __shfl_xor(v, off, 64);
    return v;
}
__device__ __forceinline__ float wave_max(float v) {
#pragma unroll
    for (int off = 32; off; off >>= 1) v = fmaxf(v, __shfl_xor(v, off, 64));
    return v;
}

// ---------------------------------------------------------------------------
// Kernel A: effective weights  Weff[j,d] = sum_c A[j,c] * W2[c,d]  (+bias row)
// grid: 3 matrices x 32 c-chunks, 256 threads (each thread owns 4 d's)
// ---------------------------------------------------------------------------
__global__ __launch_bounds__(256) void eff_weights(
    const float* __restrict__ w_vel, const float* __restrict__ b_vel,
    const float* __restrict__ w_init, const float* __restrict__ b_init,
    const float* __restrict__ wq, const float* __restrict__ bq,
    const float* __restrict__ wk, const float* __restrict__ bk,
    const float* __restrict__ wv, const float* __restrict__ bv,
    float* __restrict__ ws)
{
    const int m = blockIdx.x >> 5;
    const int chunk = blockIdx.x & 31;
    const float *A1, *bvec, *W2, *b2;
    float* dst;
    if (m == 0)      { A1 = w_vel;  bvec = b_vel;  W2 = wq; b2 = bq; dst = ws + WQE; }
    else if (m == 1) { A1 = w_init; bvec = b_init; W2 = wk; b2 = bk; dst = ws + WKE; }
    else             { A1 = w_init; bvec = b_init; W2 = wv; b2 = bv; dst = ws + WVE; }

    const int d4 = threadIdx.x * 4;
    float acc[4][4] = {{0.f,0.f,0.f,0.f},{0.f,0.f,0.f,0.f},{0.f,0.f,0.f,0.f},{0.f,0.f,0.f,0.f}};
    if (chunk == 0) {
#pragma unroll
        for (int x = 0; x < 4; ++x) acc[3][x] = b2[d4 + x];
    }
    const int c0 = chunk * 32;
    for (int c = c0; c < c0 + 32; ++c) {
        const float a0 = A1[c], a1 = A1[1024 + c], a2 = A1[2048 + c], a3 = bvec[c];
        const float4 w4 = *reinterpret_cast<const float4*>(W2 + (size_t)c * 1024 + d4);
        acc[0][0] = fmaf(a0, w4.x, acc[0][0]); acc[0][1] = fmaf(a0, w4.y, acc[0][1]);
        acc[0][2] = fmaf(a0, w4.z, acc[0][2]); acc[0][3] = fmaf(a0, w4.w, acc[0][3]);
        acc[1][0] = fmaf(a1, w4.x, acc[1][0]); acc[1][1] = fmaf(a1, w4.y, acc[1][1]);
        acc[1][2] = fmaf(a1, w4.z, acc[1][2]); acc[1][3] = fmaf(a1, w4.w, acc[1][3]);
        acc[2][0] = fmaf(a2, w4.x, acc[2][0]); acc[2][1] = fmaf(a2, w4.y, acc[2][1]);
        acc[2][2] = fmaf(a2, w4.z, acc[2][2]); acc[2][3] = fmaf(a2, w4.w, acc[2][3]);
        acc[3][0] = fmaf(a3, w4.x, acc[3][0]); acc[3][1] = fmaf(a3, w4.y, acc[3][1]);
        acc[3][2] = fmaf(a3, w4.z, acc[3][2]); acc[3][3] = fmaf(a3, w4.w, acc[3][3]);
    }
#pragma unroll
    for (int j = 0; j < 4; ++j)
#pragma unroll
        for (int x = 0; x < 4; ++x)
            atomicAdd(&dst[j * 1024 + d4 + x], acc[j][x]);
}

// ---------------------------------------------------------------------------
// Kernel B1: per-head 4x4 Grams, M_h, C_h, and global db.  16 blocks x 64 thr.
// ---------------------------------------------------------------------------
__global__ __launch_bounds__(64) void head_tensors(
    const float* __restrict__ dwc_w, const float* __restrict__ dwc_b,
    const float* __restrict__ w_proj, const float* __restrict__ b_proj,
    float* __restrict__ ws)
{
    const int h = blockIdx.x;
    const int t = threadIdx.x;
    const int d = h * 64 + t;
    float wqv[4], wkv[4], wvv[4];
#pragma unroll
    for (int j = 0; j < 4; ++j) {
        wqv[j] = ws[WQE + j * 1024 + d];
        wkv[j] = ws[WKE + j * 1024 + d];
        wvv[j] = ws[WVE + j * 1024 + d];
    }
    float wp[3];
#pragma unroll
    for (int i = 0; i < 3; ++i) wp[i] = w_proj[d * 3 + i];
    float w3[3];
#pragma unroll
    for (int k = 0; k < 3; ++k) w3[k] = dwc_w[d * 9 + k * 3 + 1];  // center column of 3x3

#pragma unroll
    for (int j = 0; j < 4; ++j)
#pragma unroll
        for (int i = 0; i < 4; ++i) {
            float g1 = wave_sum(wqv[j] * wkv[i]);
            float g2 = wave_sum(wqv[j] * wqv[i]);
            if (t == 0) {
                ws[GQK + h * 16 + j * 4 + i] = g1;
                ws[GQQ + h * 16 + j * 4 + i] = g2;
            }
        }
#pragma unroll
    for (int j = 0; j < 4; ++j)
#pragma unroll
        for (int i = 0; i < 3; ++i) {
            float mv = wave_sum(wvv[j] * wp[i]);
            if (t == 0) ws[MH_ + h * 12 + j * 3 + i] = mv;
        }
#pragma unroll
    for (int k = 0; k < 3; ++k)
#pragma unroll
        for (int j = 0; j < 4; ++j)
#pragma unroll
            for (int i = 0; i < 3; ++i) {
                float cv = wave_sum(w3[k] * wvv[j] * wp[i]);
                if (t == 0) ws[CH_ + h * 36 + k * 12 + j * 3 + i] = cv;
            }
    float dbd = dwc_b[d];
#pragma unroll
    for (int i = 0; i < 3; ++i) {
        float dv = wave_sum(dbd * wp[i]);
        if (t == 0) {
            if (h == 0) dv += b_proj[i];
            atomicAdd(&ws[DB_ + i], dv);
        }
    }
}

// ---------------------------------------------------------------------------
// Kernel B2: transpose agent_bias2 [1024,49] -> [49,1024]
// ---------------------------------------------------------------------------
__global__ __launch_bounds__(256) void transpose_b2(
    const float* __restrict__ bias2, float* __restrict__ ws)
{
    const int idx = blockIdx.x * 256 + threadIdx.x;
    if (idx < NN * NA) {
        const int n = idx / NA;
        const int a = idx - n * NA;
        ws[B2T + a * 1024 + n] = bias2[idx];
    }
}

// ---------------------------------------------------------------------------
// Main fused attention kernel: one block per (b,h). 256 threads.
// ---------------------------------------------------------------------------
__global__ __launch_bounds__(256) void attn_main(
    const float* __restrict__ Q, const float* __restrict__ K, const float* __restrict__ V,
    const float* __restrict__ bias1, float* __restrict__ ws)
{
    __shared__ __align__(16) float Qs[NN * 4];
    __shared__ __align__(16) float Ks[NN * 4];
    __shared__ __align__(16) float Vs[NN * 4];
    __shared__ __align__(16) float u1[NA * 4];
    __shared__ __align__(16) float u2[NA * 4];
    __shared__ __align__(16) float AV[NA * 4];
    __shared__ float sG1[16], sG2[16], sM[12], sC[36];

    const int bh = blockIdx.x;
    const int b = bh >> 4;
    const int h = bh & 15;
    const int tid = threadIdx.x;

    const float* Qb = Q + (size_t)b * (NN * 3);
    const float* Kb = K + (size_t)b * (NN * 3);
    const float* Vb = V + (size_t)b * (NN * 3);
    for (int n = tid; n < NN; n += 256) {
        Qs[n*4+0] = Qb[n*3+0]; Qs[n*4+1] = Qb[n*3+1]; Qs[n*4+2] = Qb[n*3+2]; Qs[n*4+3] = 1.f;
        Ks[n*4+0] = Kb[n*3+0]; Ks[n*4+1] = Kb[n*3+1]; Ks[n*4+2] = Kb[n*3+2]; Ks[n*4+3] = 1.f;
        Vs[n*4+0] = Vb[n*3+0]; Vs[n*4+1] = Vb[n*3+1]; Vs[n*4+2] = Vb[n*3+2]; Vs[n*4+3] = 1.f;
    }
    if (tid < 16)                    sG1[tid]       = ws[GQK + h * 16 + tid];
    if (tid >= 64 && tid < 80)       sG2[tid - 64]  = ws[GQQ + h * 16 + tid - 64];
    if (tid >= 128 && tid < 140)     sM[tid - 128]  = ws[MH_ + h * 12 + tid - 128];
    if (tid >= 192 && tid < 228)     sC[tid - 192]  = ws[CH_ + h * 36 + tid - 192];
    __syncthreads();

    // Phase 1: pooled agents (rank-4) and u1/u2 vectors
    if (tid < NA) {
        const int a = tid;
        const int s = (a * NN) / NA;
        const int e = ((a + 1) * NN + NA - 1) / NA;
        const float inv = 1.f / (float)(e - s);
        float p0 = 0.f, p1 = 0.f, p2 = 0.f;
        for (int n = s; n < e; ++n) {
            p0 += Qs[n*4+0]; p1 += Qs[n*4+1]; p2 += Qs[n*4+2];
        }
        const float ap[4] = {p0 * inv, p1 * inv, p2 * inv, 1.f};
#pragma unroll
        for (int i = 0; i < 4; ++i) {
            float s1 = 0.f, s2 = 0.f;
#pragma unroll
            for (int j = 0; j < 4; ++j) {
                s1 = fmaf(ap[j], sG1[j * 4 + i], s1);
                s2 = fmaf(sG2[i * 4 + j], ap[j], s2);
            }
            u1[a * 4 + i] = s1;
            u2[a * 4 + i] = s2;
        }
    }
    __syncthreads();

    // Phase 2: agent aggregation softmax over n (one agent per wave at a time)
    const int wid = tid >> 6;
    const int lane = tid & 63;
    for (int a = wid; a < NA; a += 4) {
        const float ua0 = u1[a*4+0], ua1 = u1[a*4+1], ua2 = u1[a*4+2], ua3 = u1[a*4+3];
        const float* b1p = bias1 + (size_t)a * 1024;
        float sv[16];
        float mx = -1e30f;
#pragma unroll
        for (int it = 0; it < 16; ++it) {
            const int n = it * 64 + lane;
            const float4 k4 = *reinterpret_cast<const float4*>(Ks + n * 4);
            float s = fmaf(ua0, k4.x, fmaf(ua1, k4.y, fmaf(ua2, k4.z, ua3 * k4.w)));
            s += b1p[n];
            sv[it] = s;
            mx = fmaxf(mx, s);
        }
        mx = wave_max(mx);
        float l = 0.f, v0 = 0.f, v1 = 0.f, v2 = 0.f, v3 = 0.f;
#pragma unroll
        for (int it = 0; it < 16; ++it) {
            const int n = it * 64 + lane;
            const float e = __expf(sv[it] - mx);
            const float4 w4 = *reinterpret_cast<const float4*>(Vs + n * 4);
            l += e;
            v0 = fmaf(e, w4.x, v0); v1 = fmaf(e, w4.y, v1);
            v2 = fmaf(e, w4.z, v2); v3 = fmaf(e, w4.w, v3);
        }
        l = wave_sum(l);
        v0 = wave_sum(v0); v1 = wave_sum(v1); v2 = wave_sum(v2); v3 = wave_sum(v3);
        if (lane == 0) {
            const float inv = 1.f / l;
            AV[a*4+0] = v0 * inv; AV[a*4+1] = v1 * inv;
            AV[a*4+2] = v2 * inv; AV[a*4+3] = v3 * inv;
        }
    }
    __syncthreads();

    // Phase 3: broadcast softmax over agents, output contribution + dwc residual
    float* accD = ws + ACC;
    for (int n = tid; n < NN; n += 256) {
        const float4 q4 = *reinterpret_cast<const float4*>(Qs + n * 4);
        const float* b2p = ws + B2T + n;
        float mx = -1e30f;
        for (int a = 0; a < NA; ++a) {
            const float4 u = *reinterpret_cast<const float4*>(u2 + a * 4);
            const float s = fmaf(q4.x, u.x, fmaf(q4.y, u.y, fmaf(q4.z, u.z, q4.w * u.w)))
                            + b2p[a * 1024];
            mx = fmaxf(mx, s);
        }
        float l = 0.f, o0 = 0.f, o1 = 0.f, o2 = 0.f, o3 = 0.f;
        for (int a = 0; a < NA; ++a) {
            const float4 u = *reinterpret_cast<const float4*>(u2 + a * 4);
            const float s = fmaf(q4.x, u.x, fmaf(q4.y, u.y, fmaf(q4.z, u.z, q4.w * u.w)))
                            + b2p[a * 1024];
            const float e = __expf(s - mx);
            const float4 av = *reinterpret_cast<const float4*>(AV + a * 4);
            l += e;
            o0 = fmaf(e, av.x, o0); o1 = fmaf(e, av.y, o1);
            o2 = fmaf(e, av.z, o2); o3 = fmaf(e, av.w, o3);
        }
        const float invl = 1.f / l;
        o0 *= invl; o1 *= invl; o2 *= invl; o3 *= invl;

        float r0 = o0*sM[0] + o1*sM[3] + o2*sM[6] + o3*sM[9];
        float r1 = o0*sM[1] + o1*sM[4] + o2*sM[7] + o3*sM[10];
        float r2 = o0*sM[2] + o1*sM[5] + o2*sM[8] + o3*sM[11];

#pragma unroll
        for (int k = 0; k < 3; ++k) {
            const int n2 = n + k - 1;
            if ((unsigned)n2 < (unsigned)NN) {
                const float4 w4 = *reinterpret_cast<const float4*>(Vs + n2 * 4);
                const float* Ck = sC + k * 12;
                r0 += w4.x*Ck[0] + w4.y*Ck[3] + w4.z*Ck[6] + w4.w*Ck[9];
                r1 += w4.x*Ck[1] + w4.y*Ck[4] + w4.z*Ck[7] + w4.w*Ck[10];
                r2 += w4.x*Ck[2] + w4.y*Ck[5] + w4.z*Ck[8] + w4.w*Ck[11];
            }
        }
        float* dst = accD + (size_t)b * (NN * 3) + n * 3;
        atomicAdd(dst + 0, r0);
        atomicAdd(dst + 1, r1);
        atomicAdd(dst + 2, r2);
    }
}

// ---------------------------------------------------------------------------
// Finalize: out[b,i,n] = acc[b,n,i] + db[i]
// ---------------------------------------------------------------------------
__global__ __launch_bounds__(256) void finalize(
    const float* __restrict__ ws, float* __restrict__ out)
{
    const int o = blockIdx.x * 256 + threadIdx.x;
    if (o < NB * 3 * NN) {
        const int b = o / (3 * NN);
        const int r = o - b * (3 * NN);
        const int i = r >> 10;
        const int n = r & 1023;
        out[o] = ws[ACC + b * (NN * 3) + n * 3 + i] + ws[DB_ + i];
    }
}

extern "C" void kernel_launch(void* const* d_in, const int* in_sizes, int n_in,
                              void* d_out, int out_size, void* d_ws, size_t ws_size,
                              hipStream_t stream) {
    (void)in_sizes; (void)n_in; (void)out_size; (void)ws_size;
    const float* Q       = (const float*)d_in[0];
    const float* K       = (const float*)d_in[1];
    const float* V       = (const float*)d_in[2];
    const float* w_vel   = (const float*)d_in[3];
    const float* b_vel   = (const float*)d_in[4];
    const float* w_init  = (const float*)d_in[5];
    const float* b_init  = (const float*)d_in[6];
    const float* wq      = (const float*)d_in[7];
    const float* bq      = (const float*)d_in[8];
    const float* wk      = (const float*)d_in[9];
    const float* bk      = (const float*)d_in[10];
    const float* wv      = (const float*)d_in[11];
    const float* bv      = (const float*)d_in[12];
    const float* bias1   = (const float*)d_in[13];
    const float* bias2   = (const float*)d_in[14];
    const float* dwc_w   = (const float*)d_in[15];
    const float* dwc_b   = (const float*)d_in[16];
    const float* w_proj  = (const float*)d_in[17];
    const float* b_proj  = (const float*)d_in[18];
    float* ws = (float*)d_ws;
    float* out = (float*)d_out;

    hipMemsetAsync(d_ws, 0, WS_FLOATS * sizeof(float), stream);
    eff_weights<<<96, 256, 0, stream>>>(w_vel, b_vel, w_init, b_init,
                                        wq, bq, wk, bk, wv, bv, ws);
    head_tensors<<<16, 64, 0, stream>>>(dwc_w, dwc_b, w_proj, b_proj, ws);
    transpose_b2<<<196, 256, 0, stream>>>(bias2, ws);
    attn_main<<<NB * NH, 256, 0, stream>>>(Q, K, V, bias1, ws);
    finalize<<<384, 256, 0, stream>>>(ws, out);
}

// Round 2
// 174.759 us; speedup vs baseline: 1.5247x; 1.5247x over previous
//
#include <hip/hip_runtime.h>

// Problem constants
#define NB 32
#define NN 1024
#define NH 16
#define NA 49

// Workspace layout (float offsets)
#define WQE 0          // [4][1024] effective Q weights (rows 0-2 = w_vel@wq, row 3 = bias)
#define WKE 4096
#define WVE 8192
#define GQK 12288      // [16][4][4]
#define GQQ 12544      // [16][4][4]
#define MH_ 12800      // [16][4][3]
#define CH_ 12992      // [16][3][4][3]
#define DB_ 13568      // [3]
#define ZERO_FLOATS 13571
#define U2_ 16384      // [32][16][49][4]
#define AV_ 116736     // [32][16][49][4]

__device__ __forceinline__ float wave_sum(float v) {
#pragma unroll
    for (int off = 32; off; off >>= 1) v += __shfl_xor(v, off, 64);
    return v;
}
__device__ __forceinline__ float wave_max(float v) {
#pragma unroll
    for (int off = 32; off; off >>= 1) v = fmaxf(v, __shfl_xor(v, off, 64));
    return v;
}

// ---------------------------------------------------------------------------
// Kernel A: effective weights  Weff[j,d] = sum_c A[j,c] * W2[c,d]  (+bias row)
// ---------------------------------------------------------------------------
__global__ __launch_bounds__(256) void eff_weights(
    const float* __restrict__ w_vel, const float* __restrict__ b_vel,
    const float* __restrict__ w_init, const float* __restrict__ b_init,
    const float* __restrict__ wq, const float* __restrict__ bq,
    const float* __restrict__ wk, const float* __restrict__ bk,
    const float* __restrict__ wv, const float* __restrict__ bv,
    float* __restrict__ ws)
{
    const int m = blockIdx.x >> 5;
    const int chunk = blockIdx.x & 31;
    const float *A1, *bvec, *W2, *b2;
    float* dst;
    if (m == 0)      { A1 = w_vel;  bvec = b_vel;  W2 = wq; b2 = bq; dst = ws + WQE; }
    else if (m == 1) { A1 = w_init; bvec = b_init; W2 = wk; b2 = bk; dst = ws + WKE; }
    else             { A1 = w_init; bvec = b_init; W2 = wv; b2 = bv; dst = ws + WVE; }

    const int d4 = threadIdx.x * 4;
    float acc[4][4] = {{0.f,0.f,0.f,0.f},{0.f,0.f,0.f,0.f},{0.f,0.f,0.f,0.f},{0.f,0.f,0.f,0.f}};
    if (chunk == 0) {
#pragma unroll
        for (int x = 0; x < 4; ++x) acc[3][x] = b2[d4 + x];
    }
    const int c0 = chunk * 32;
    for (int c = c0; c < c0 + 32; ++c) {
        const float a0 = A1[c], a1 = A1[1024 + c], a2 = A1[2048 + c], a3 = bvec[c];
        const float4 w4 = *reinterpret_cast<const float4*>(W2 + (size_t)c * 1024 + d4);
        acc[0][0] = fmaf(a0, w4.x, acc[0][0]); acc[0][1] = fmaf(a0, w4.y, acc[0][1]);
        acc[0][2] = fmaf(a0, w4.z, acc[0][2]); acc[0][3] = fmaf(a0, w4.w, acc[0][3]);
        acc[1][0] = fmaf(a1, w4.x, acc[1][0]); acc[1][1] = fmaf(a1, w4.y, acc[1][1]);
        acc[1][2] = fmaf(a1, w4.z, acc[1][2]); acc[1][3] = fmaf(a1, w4.w, acc[1][3]);
        acc[2][0] = fmaf(a2, w4.x, acc[2][0]); acc[2][1] = fmaf(a2, w4.y, acc[2][1]);
        acc[2][2] = fmaf(a2, w4.z, acc[2][2]); acc[2][3] = fmaf(a2, w4.w, acc[2][3]);
        acc[3][0] = fmaf(a3, w4.x, acc[3][0]); acc[3][1] = fmaf(a3, w4.y, acc[3][1]);
        acc[3][2] = fmaf(a3, w4.z, acc[3][2]); acc[3][3] = fmaf(a3, w4.w, acc[3][3]);
    }
#pragma unroll
    for (int j = 0; j < 4; ++j)
#pragma unroll
        for (int x = 0; x < 4; ++x)
            atomicAdd(&dst[j * 1024 + d4 + x], acc[j][x]);
}

// ---------------------------------------------------------------------------
// Kernel B: per-head 4x4 Grams, M_h, C_h, and global db.  16 blocks x 64 thr.
// ---------------------------------------------------------------------------
__global__ __launch_bounds__(64) void head_tensors(
    const float* __restrict__ dwc_w, const float* __restrict__ dwc_b,
    const float* __restrict__ w_proj, const float* __restrict__ b_proj,
    float* __restrict__ ws)
{
    const int h = blockIdx.x;
    const int t = threadIdx.x;
    const int d = h * 64 + t;
    float wqv[4], wkv[4], wvv[4];
#pragma unroll
    for (int j = 0; j < 4; ++j) {
        wqv[j] = ws[WQE + j * 1024 + d];
        wkv[j] = ws[WKE + j * 1024 + d];
        wvv[j] = ws[WVE + j * 1024 + d];
    }
    float wp[3];
#pragma unroll
    for (int i = 0; i < 3; ++i) wp[i] = w_proj[d * 3 + i];
    float w3[3];
#pragma unroll
    for (int k = 0; k < 3; ++k) w3[k] = dwc_w[d * 9 + k * 3 + 1];

#pragma unroll
    for (int j = 0; j < 4; ++j)
#pragma unroll
        for (int i = 0; i < 4; ++i) {
            float g1 = wave_sum(wqv[j] * wkv[i]);
            float g2 = wave_sum(wqv[j] * wqv[i]);
            if (t == 0) {
                ws[GQK + h * 16 + j * 4 + i] = g1;
                ws[GQQ + h * 16 + j * 4 + i] = g2;
            }
        }
#pragma unroll
    for (int j = 0; j < 4; ++j)
#pragma unroll
        for (int i = 0; i < 3; ++i) {
            float mv = wave_sum(wvv[j] * wp[i]);
            if (t == 0) ws[MH_ + h * 12 + j * 3 + i] = mv;
        }
#pragma unroll
    for (int k = 0; k < 3; ++k)
#pragma unroll
        for (int j = 0; j < 4; ++j)
#pragma unroll
            for (int i = 0; i < 3; ++i) {
                float cv = wave_sum(w3[k] * wvv[j] * wp[i]);
                if (t == 0) ws[CH_ + h * 36 + k * 12 + j * 3 + i] = cv;
            }
    float dbd = dwc_b[d];
#pragma unroll
    for (int i = 0; i < 3; ++i) {
        float dv = wave_sum(dbd * wp[i]);
        if (t == 0) {
            if (h == 0) dv += b_proj[i];
            atomicAdd(&ws[DB_ + i], dv);
        }
    }
}

// ---------------------------------------------------------------------------
// k_agg: one block per (b,h). Pool + u1/u2 + agent-aggregation softmax.
// Writes u2[b][h][a][4] and AV[b][h][a][4] to ws.
// ---------------------------------------------------------------------------
__global__ __launch_bounds__(256) void k_agg(
    const float* __restrict__ Q, const float* __restrict__ K, const float* __restrict__ V,
    const float* __restrict__ bias1, float* __restrict__ ws)
{
    __shared__ __align__(16) float Qs[NN * 4];
    __shared__ __align__(16) float Ks[NN * 4];
    __shared__ __align__(16) float Vs[NN * 4];
    __shared__ __align__(16) float u1s[NA * 4];
    __shared__ float sG1[16], sG2[16];

    const int bh = blockIdx.x;
    const int b = bh >> 4;
    const int h = bh & 15;
    const int tid = threadIdx.x;

    const float* Qb = Q + (size_t)b * (NN * 3);
    const float* Kb = K + (size_t)b * (NN * 3);
    const float* Vb = V + (size_t)b * (NN * 3);
    for (int n = tid; n < NN; n += 256) {
        Qs[n*4+0] = Qb[n*3+0]; Qs[n*4+1] = Qb[n*3+1]; Qs[n*4+2] = Qb[n*3+2]; Qs[n*4+3] = 1.f;
        Ks[n*4+0] = Kb[n*3+0]; Ks[n*4+1] = Kb[n*3+1]; Ks[n*4+2] = Kb[n*3+2]; Ks[n*4+3] = 1.f;
        Vs[n*4+0] = Vb[n*3+0]; Vs[n*4+1] = Vb[n*3+1]; Vs[n*4+2] = Vb[n*3+2]; Vs[n*4+3] = 1.f;
    }
    if (tid < 16)               sG1[tid]      = ws[GQK + h * 16 + tid];
    if (tid >= 64 && tid < 80)  sG2[tid - 64] = ws[GQQ + h * 16 + tid - 64];
    __syncthreads();

    // Phase 1: pooled agents (rank-4), u1 (LDS), u2 (global for k_bc)
    if (tid < NA) {
        const int a = tid;
        const int s = (a * NN) / NA;
        const int e = ((a + 1) * NN + NA - 1) / NA;
        const float inv = 1.f / (float)(e - s);
        float p0 = 0.f, p1 = 0.f, p2 = 0.f;
        for (int n = s; n < e; ++n) {
            p0 += Qs[n*4+0]; p1 += Qs[n*4+1]; p2 += Qs[n*4+2];
        }
        const float ap[4] = {p0 * inv, p1 * inv, p2 * inv, 1.f};
        float* u2g = ws + U2_ + (size_t)(bh * NA + a) * 4;
#pragma unroll
        for (int i = 0; i < 4; ++i) {
            float s1 = 0.f, s2 = 0.f;
#pragma unroll
            for (int j = 0; j < 4; ++j) {
                s1 = fmaf(ap[j], sG1[j * 4 + i], s1);
                s2 = fmaf(sG2[i * 4 + j], ap[j], s2);
            }
            u1s[a * 4 + i] = s1;
            u2g[i] = s2;
        }
    }
    __syncthreads();

    // Phase 2: agent aggregation softmax over n (one agent per wave at a time)
    const int wid = tid >> 6;
    const int lane = tid & 63;
    for (int a = wid; a < NA; a += 4) {
        const float ua0 = u1s[a*4+0], ua1 = u1s[a*4+1], ua2 = u1s[a*4+2], ua3 = u1s[a*4+3];
        const float* b1p = bias1 + (size_t)a * NN;
        float sv[16];
        float mx = -1e30f;
#pragma unroll
        for (int it = 0; it < 16; ++it) {
            const int n = it * 64 + lane;
            const float4 k4 = *reinterpret_cast<const float4*>(Ks + n * 4);
            float s = fmaf(ua0, k4.x, fmaf(ua1, k4.y, fmaf(ua2, k4.z, ua3 * k4.w)));
            s += b1p[n];
            sv[it] = s;
            mx = fmaxf(mx, s);
        }
        mx = wave_max(mx);
        float l = 0.f, v0 = 0.f, v1 = 0.f, v2 = 0.f, v3 = 0.f;
#pragma unroll
        for (int it = 0; it < 16; ++it) {
            const int n = it * 64 + lane;
            const float e = __expf(sv[it] - mx);
            const float4 w4 = *reinterpret_cast<const float4*>(Vs + n * 4);
            l += e;
            v0 = fmaf(e, w4.x, v0); v1 = fmaf(e, w4.y, v1);
            v2 = fmaf(e, w4.z, v2); v3 = fmaf(e, w4.w, v3);
        }
        l = wave_sum(l);
        v0 = wave_sum(v0); v1 = wave_sum(v1); v2 = wave_sum(v2); v3 = wave_sum(v3);
        if (lane == 0) {
            const float inv = 1.f / l;
            float* avg = ws + AV_ + (size_t)(bh * NA + a) * 4;
            avg[0] = v0 * inv; avg[1] = v1 * inv; avg[2] = v2 * inv; avg[3] = v3 * inv;
        }
    }
}

// ---------------------------------------------------------------------------
// k_bc: broadcast softmax + dwc residual + projection + transpose, final out.
// grid = B * (N/16); block 256 = 16 n x 16 h; tid = nl*16 + h.
// ---------------------------------------------------------------------------
__global__ __launch_bounds__(256) void k_bc(
    const float* __restrict__ Q, const float* __restrict__ V,
    const float* __restrict__ bias2, const float* __restrict__ ws,
    float* __restrict__ out)
{
    __shared__ __align__(16) float u2s[NH * NA * 4];   // 3136
    __shared__ __align__(16) float avs[NH * NA * 4];   // 3136
    __shared__ __align__(16) float mcs[768];           // sM[16][12] then sC[16][36]
    __shared__ float b2s[16 * NA];                     // 784, [nl][a]
    __shared__ __align__(16) float qs[16 * 4];

    const int blk = blockIdx.x;
    const int b = blk >> 6;
    const int n0 = (blk & 63) * 16;
    const int tid = threadIdx.x;
    const int nl = tid >> 4;
    const int h = tid & 15;
    const int n = n0 + nl;

    // Cooperative staging (all coalesced float4 except b2s)
    const float4* u2g = reinterpret_cast<const float4*>(ws + U2_ + (size_t)b * (NH * NA * 4));
    const float4* avg = reinterpret_cast<const float4*>(ws + AV_ + (size_t)b * (NH * NA * 4));
    for (int i = tid; i < NH * NA; i += 256) {
        reinterpret_cast<float4*>(u2s)[i] = u2g[i];
        reinterpret_cast<float4*>(avs)[i] = avg[i];
    }
    for (int i = tid; i < 16 * NA; i += 256) b2s[i] = bias2[(size_t)n0 * NA + i];
    if (tid < 192) reinterpret_cast<float4*>(mcs)[tid] =
        reinterpret_cast<const float4*>(ws + MH_)[tid];
    if (tid < 16) {
        const float* qp = Q + (size_t)b * (NN * 3) + (size_t)(n0 + tid) * 3;
        qs[tid*4+0] = qp[0]; qs[tid*4+1] = qp[1]; qs[tid*4+2] = qp[2]; qs[tid*4+3] = 1.f;
    }
    __syncthreads();

    const float q0 = qs[nl*4+0], q1 = qs[nl*4+1], q2 = qs[nl*4+2], q3 = qs[nl*4+3];
    const float* u2h = u2s + h * (NA * 4);
    const float* avh = avs + h * (NA * 4);
    const float* b2r = b2s + nl * NA;

    float mx = -1e30f;
    for (int a = 0; a < NA; ++a) {
        const float4 u = *reinterpret_cast<const float4*>(u2h + a * 4);
        const float s = fmaf(q0, u.x, fmaf(q1, u.y, fmaf(q2, u.z, q3 * u.w))) + b2r[a];
        mx = fmaxf(mx, s);
    }
    float l = 0.f, o0 = 0.f, o1 = 0.f, o2 = 0.f, o3 = 0.f;
    for (int a = 0; a < NA; ++a) {
        const float4 u = *reinterpret_cast<const float4*>(u2h + a * 4);
        const float s = fmaf(q0, u.x, fmaf(q1, u.y, fmaf(q2, u.z, q3 * u.w))) + b2r[a];
        const float e = __expf(s - mx);
        const float4 av = *reinterpret_cast<const float4*>(avh + a * 4);
        l += e;
        o0 = fmaf(e, av.x, o0); o1 = fmaf(e, av.y, o1);
        o2 = fmaf(e, av.z, o2); o3 = fmaf(e, av.w, o3);
    }
    const float invl = 1.f / l;
    o0 *= invl; o1 *= invl; o2 *= invl; o3 *= invl;

    const float* M = mcs + h * 12;
    float r0 = o0*M[0] + o1*M[3] + o2*M[6] + o3*M[9];
    float r1 = o0*M[1] + o1*M[4] + o2*M[7] + o3*M[10];
    float r2 = o0*M[2] + o1*M[5] + o2*M[8] + o3*M[11];

    const float* C = mcs + 192 + h * 36;
    const float* Vb = V + (size_t)b * (NN * 3);
#pragma unroll
    for (int k = 0; k < 3; ++k) {
        const int n2 = n + k - 1;
        if ((unsigned)n2 < (unsigned)NN) {
            const float v0 = Vb[n2*3+0], v1 = Vb[n2*3+1], v2 = Vb[n2*3+2];
            const float* Ck = C + k * 12;
            r0 += v0*Ck[0] + v1*Ck[3] + v2*Ck[6] + Ck[9];
            r1 += v0*Ck[1] + v1*Ck[4] + v2*Ck[7] + Ck[10];
            r2 += v0*Ck[2] + v1*Ck[5] + v2*Ck[8] + Ck[11];
        }
    }
    // reduce over the 16 h lanes (contiguous within the wave)
#pragma unroll
    for (int off = 8; off; off >>= 1) {
        r0 += __shfl_xor(r0, off, 64);
        r1 += __shfl_xor(r1, off, 64);
        r2 += __shfl_xor(r2, off, 64);
    }
    if (h == 0) {
        float* ob = out + (size_t)b * (3 * NN);
        ob[0 * NN + n] = r0 + ws[DB_ + 0];
        ob[1 * NN + n] = r1 + ws[DB_ + 1];
        ob[2 * NN + n] = r2 + ws[DB_ + 2];
    }
}

extern "C" void kernel_launch(void* const* d_in, const int* in_sizes, int n_in,
                              void* d_out, int out_size, void* d_ws, size_t ws_size,
                              hipStream_t stream) {
    (void)in_sizes; (void)n_in; (void)out_size; (void)ws_size;
    const float* Q       = (const float*)d_in[0];
    const float* K       = (const float*)d_in[1];
    const float* V       = (const float*)d_in[2];
    const float* w_vel   = (const float*)d_in[3];
    const float* b_vel   = (const float*)d_in[4];
    const float* w_init  = (const float*)d_in[5];
    const float* b_init  = (const float*)d_in[6];
    const float* wq      = (const float*)d_in[7];
    const float* bq      = (const float*)d_in[8];
    const float* wk      = (const float*)d_in[9];
    const float* bk      = (const float*)d_in[10];
    const float* wv      = (const float*)d_in[11];
    const float* bv      = (const float*)d_in[12];
    const float* bias1   = (const float*)d_in[13];
    const float* bias2   = (const float*)d_in[14];
    const float* dwc_w   = (const float*)d_in[15];
    const float* dwc_b   = (const float*)d_in[16];
    const float* w_proj  = (const float*)d_in[17];
    const float* b_proj  = (const float*)d_in[18];
    float* ws = (float*)d_ws;
    float* out = (float*)d_out;

    hipMemsetAsync(d_ws, 0, ZERO_FLOATS * sizeof(float), stream);
    eff_weights<<<96, 256, 0, stream>>>(w_vel, b_vel, w_init, b_init,
                                        wq, bq, wk, bk, wv, bv, ws);
    head_tensors<<<16, 64, 0, stream>>>(dwc_w, dwc_b, w_proj, b_proj, ws);
    k_agg<<<NB * NH, 256, 0, stream>>>(Q, K, V, bias1, ws);
    k_bc<<<NB * (NN / 16), 256, 0, stream>>>(Q, V, bias2, ws, out);
}